// Round 5
// baseline (1772.371 us; speedup 1.0000x reference)
//
#include <hip/hip_runtime.h>
#include <cstdint>

// ---------------------------------------------------------------------------
// DDPM + VAE query encoder, MI355X round 5 (fp32)
// Changes vs r4 (k_ddpm only):
//  - Weights loaded via asm-volatile global_load blocks (cannot be remat/sunk
//    into the 200-step loop; r2-r4 compiler re-loaded them from L1 each step,
//    VGPR_Count stuck at 88).
//  - amdgpu_waves_per_eu(2,2): 256-VGPR budget so 128 resident weights fit.
//  - 4-way split accumulators per GEMV row: 8 independent FMA chains
//    (r4 had 2 chains x 64-deep @ ~4cyc latency = issue starvation).
// Numerics identical to the passing r3/r4.
// ---------------------------------------------------------------------------

#define DEVI __device__ __forceinline__

DEVI uint32_t rotl32(uint32_t x, uint32_t r) { return (x << r) | (x >> (32u - r)); }

// JAX/Random123 threefry2x32, 20 rounds.
DEVI void threefry2x32(uint32_t k0, uint32_t k1, uint32_t x0, uint32_t x1,
                       uint32_t &o0, uint32_t &o1)
{
  const uint32_t ks2 = k0 ^ k1 ^ 0x1BD11BDAu;
  x0 += k0; x1 += k1;
#define TFR(r) { x0 += x1; x1 = rotl32(x1, r); x1 ^= x0; }
  TFR(13u) TFR(15u) TFR(26u) TFR(6u)   x0 += k1;  x1 += ks2 + 1u;
  TFR(17u) TFR(29u) TFR(16u) TFR(24u)  x0 += ks2; x1 += k0 + 2u;
  TFR(13u) TFR(15u) TFR(26u) TFR(6u)   x0 += k0;  x1 += k1 + 3u;
  TFR(17u) TFR(29u) TFR(16u) TFR(24u)  x0 += k1;  x1 += ks2 + 4u;
  TFR(13u) TFR(15u) TFR(26u) TFR(6u)   x0 += ks2; x1 += k0 + 5u;
#undef TFR
  o0 = x0; o1 = x1;
}

// partitionable random_bits(32) for flat index j (size < 2^32 -> hi word 0)
DEVI uint32_t jax_random_bits32(uint32_t k0, uint32_t k1, uint32_t j)
{
  uint32_t a, b;
  threefry2x32(k0, k1, 0u, j, a, b);
  return a ^ b;
}

// bits -> uniform [-1+eps, 1) -> sqrt(2)*erfinv(u) (XLA/Giles polynomial).
DEVI float jax_bits_to_normal(uint32_t bits)
{
  const float LO = -0.99999994f;              // nextafter(-1,0) in f32
  float f = __uint_as_float((bits >> 9) | 0x3f800000u) - 1.0f;
  float u = fmaxf(LO, f * 2.0f + LO);
  float w = -__logf((1.0f - u) * (1.0f + u));
  float p;
  if (w < 5.0f) {
    w = w - 2.5f;
    p =              2.81022636e-08f;
    p = fmaf(p, w,   3.43273939e-07f);
    p = fmaf(p, w,  -3.5233877e-06f);
    p = fmaf(p, w,  -4.39150654e-06f);
    p = fmaf(p, w,   0.00021858087f);
    p = fmaf(p, w,  -0.00125372503f);
    p = fmaf(p, w,  -0.00417768164f);
    p = fmaf(p, w,   0.246640727f);
    p = fmaf(p, w,   1.50140941f);
  } else {
    w = sqrtf(w) - 3.0f;
    p =             -0.000200214257f;
    p = fmaf(p, w,   0.000100950558f);
    p = fmaf(p, w,   0.00134934322f);
    p = fmaf(p, w,  -0.00367342844f);
    p = fmaf(p, w,   0.00573950773f);
    p = fmaf(p, w,  -0.0076224613f);
    p = fmaf(p, w,   0.00943887047f);
    p = fmaf(p, w,   1.00167406f);
    p = fmaf(p, w,   2.83297682f);
  }
  return 1.41421356237f * (p * u);
}

// ---------------------------------------------------------------------------
// K_pool: 2048 blocks x 256 threads; wave per row, lane per dim.
__global__ __launch_bounds__(256)
void k_pool(const int* __restrict__ seq, const float* __restrict__ emb,
            float* __restrict__ pooled)
{
  const int lane = threadIdx.x & 63;
  const int r    = blockIdx.x * 4 + (threadIdx.x >> 6);   // 0..8191
  const int* row = seq + r * 100;
  float s = 0.f;
  int cnt = 0;
  for (int l = 0; l < 100; ++l) {
    int id = row[l];
    cnt += (id != 0);
    s += emb[id * 64 + lane];
  }
  pooled[r * 64 + lane] = s / sqrtf((float)cnt);
}

// ---------------------------------------------------------------------------
// K_enc: 1024 blocks x 256 threads; 8 rows per block.
__global__ __launch_bounds__(256)
void k_enc(const float* __restrict__ pooled,
           const float* __restrict__ W1, const float* __restrict__ b1,
           const float* __restrict__ W2, const float* __restrict__ b2,
           const float* __restrict__ Wc, const float* __restrict__ bc,
           float* __restrict__ cproj)
{
  __shared__ float p_s[8][64];
  __shared__ float h_s[8][256];
  __shared__ float mu_s[8][64];
  const int tid = threadIdx.x;
  const int r0  = blockIdx.x * 8;

  for (int i = tid; i < 8 * 64; i += 256)
    p_s[i >> 6][i & 63] = pooled[r0 * 64 + i];
  __syncthreads();

  float hacc[8];
#pragma unroll
  for (int r = 0; r < 8; ++r) hacc[r] = b1[tid];
  for (int k = 0; k < 64; ++k) {
    float w = W1[k * 256 + tid];
#pragma unroll
    for (int r = 0; r < 8; ++r) hacc[r] = fmaf(p_s[r][k], w, hacc[r]);
  }
#pragma unroll
  for (int r = 0; r < 8; ++r) h_s[r][tid] = fmaxf(hacc[r], 0.f);
  __syncthreads();

#pragma unroll
  for (int pass = 0; pass < 2; ++pass) {
    int r = pass * 4 + (tid >> 6);
    int j = tid & 63;
    float acc = b2[j];
    for (int k = 0; k < 256; ++k)
      acc = fmaf(h_s[r][k], W2[k * 128 + j], acc);
    mu_s[r][j] = acc;
  }
  __syncthreads();

#pragma unroll
  for (int pass = 0; pass < 2; ++pass) {
    int r = pass * 4 + (tid >> 6);
    int j = tid & 63;
    float acc = bc[j];
    for (int k = 0; k < 64; ++k)
      acc = fmaf(mu_s[r][k], Wc[k * 64 + j], acc);
    cproj[(r0 + r) * 64 + j] = acc;
  }
}

// ---------------------------------------------------------------------------
// K_sched: single thread, f32 mimic of the jnp schedule.
__global__ void k_sched(float* __restrict__ sched)
{
  if (threadIdx.x != 0 || blockIdx.x != 0) return;
  const float start = (float)(5.0 * 1e-4);
  const float stop  = (float)(5.0 * 0.02);
  const float delta = stop - start;
  float prod = 1.f;
  for (int i = 0; i < 200; ++i) {
    float beta  = start + ((float)i * delta) / 199.0f;
    float alpha = 1.0f - beta;
    float acp_prev = prod;
    prod = prod * alpha;
    float acp = prod;
    float om  = 1.0f - acp;
    sched[i]       = sqrtf(1.0f / acp);
    sched[200 + i] = sqrtf(1.0f / acp - 1.0f);
    sched[400 + i] = beta * sqrtf(acp_prev) / om;
    sched[600 + i] = (1.0f - acp_prev) * sqrtf(alpha) / om;
    float pv = beta * (1.0f - acp_prev) / om;
    sched[800 + i] = (i > 0) ? sqrtf(pv) : 0.0f;
  }
}

// ---------------------------------------------------------------------------
// K_tproj: 200 blocks x 64 threads; tpb[t][d] = temb(t)@W_t + b_t + b_in
__global__ __launch_bounds__(64)
void k_tproj(const float* __restrict__ Wt, const float* __restrict__ bt,
             const float* __restrict__ bin, float* __restrict__ tpb)
{
  __shared__ float temb[64];
  const int t = blockIdx.x;
  const int d = threadIdx.x;
  const float lg = logf(10000.0f);
  {
    int i = d & 31;
    float fr  = expf((-lg * (float)i) / 32.0f);
    float ang = (float)t * fr;
    temb[d] = (d < 32) ? cosf(ang) : sinf(ang);
  }
  __syncthreads();
  float acc = bt[d] + bin[d];
  for (int k = 0; k < 64; ++k)
    acc = fmaf(temb[k], Wt[k * 64 + d], acc);
  tpb[t * 64 + d] = acc;
}

// ---------------------------------------------------------------------------
// asm-volatile group load: 8 weights -> VGPRs, un-rematerializable.
#define LOADG8(W, P, B)                                                        \
  {                                                                            \
    const float *q0 = (P) + ((B) + 0) * 64 + lane;                             \
    const float *q1 = (P) + ((B) + 1) * 64 + lane;                             \
    const float *q2 = (P) + ((B) + 2) * 64 + lane;                             \
    const float *q3 = (P) + ((B) + 3) * 64 + lane;                             \
    const float *q4 = (P) + ((B) + 4) * 64 + lane;                             \
    const float *q5 = (P) + ((B) + 5) * 64 + lane;                             \
    const float *q6 = (P) + ((B) + 6) * 64 + lane;                             \
    const float *q7 = (P) + ((B) + 7) * 64 + lane;                             \
    asm volatile(                                                              \
        "global_load_dword %0, %8, off\n\t"                                    \
        "global_load_dword %1, %9, off\n\t"                                    \
        "global_load_dword %2, %10, off\n\t"                                   \
        "global_load_dword %3, %11, off\n\t"                                   \
        "global_load_dword %4, %12, off\n\t"                                   \
        "global_load_dword %5, %13, off\n\t"                                   \
        "global_load_dword %6, %14, off\n\t"                                   \
        "global_load_dword %7, %15, off\n\t"                                   \
        "s_waitcnt vmcnt(0)"                                                   \
        : "=&v"(W[(B) + 0]), "=&v"(W[(B) + 1]), "=&v"(W[(B) + 2]),             \
          "=&v"(W[(B) + 3]), "=&v"(W[(B) + 4]), "=&v"(W[(B) + 5]),             \
          "=&v"(W[(B) + 6]), "=&v"(W[(B) + 7])                                 \
        : "v"(q0), "v"(q1), "v"(q2), "v"(q3), "v"(q4), "v"(q5), "v"(q6),       \
          "v"(q7));                                                            \
  }

// K_ddpm: 1024 blocks x 256 threads; wave handles rows (p, p+4096), lane = dim.
// waves_per_eu(2,2): 256-VGPR budget; ~210 live -> no spill needed.
__global__
__attribute__((amdgpu_flat_work_group_size(256, 256), amdgpu_waves_per_eu(2, 2)))
void k_ddpm(const float* __restrict__ Win, const float* __restrict__ Wout,
            const float* __restrict__ bout,
            const float* __restrict__ cproj, const float* __restrict__ tpb,
            const float* __restrict__ sched, float* __restrict__ out)
{
  const int lane = threadIdx.x & 63;
  const int p    = blockIdx.x * 4 + (threadIdx.x >> 6);    // 0..4095
  const uint32_t jA = (uint32_t)(p * 64 + lane);           // flat idx, < 262144
  const uint32_t jB = jA + 262144u;                        // row p+4096

  float Wi[64], Wo[64];
  LOADG8(Wi, Win, 0)  LOADG8(Wi, Win, 8)  LOADG8(Wi, Win, 16) LOADG8(Wi, Win, 24)
  LOADG8(Wi, Win, 32) LOADG8(Wi, Win, 40) LOADG8(Wi, Win, 48) LOADG8(Wi, Win, 56)
  LOADG8(Wo, Wout, 0)  LOADG8(Wo, Wout, 8)  LOADG8(Wo, Wout, 16) LOADG8(Wo, Wout, 24)
  LOADG8(Wo, Wout, 32) LOADG8(Wo, Wout, 40) LOADG8(Wo, Wout, 48) LOADG8(Wo, Wout, 56)

  const float bo  = bout[lane];
  const float cpA = cproj[p * 64 + lane];
  const float cpB = cproj[(p + 4096) * 64 + lane];

  // x_init = normal(key(1)=[0,1]), partitionable bits
  float xA = jax_bits_to_normal(jax_random_bits32(0u, 1u, jA));
  float xB = jax_bits_to_normal(jax_random_bits32(0u, 1u, jB));

  const float* sr_a   = sched;
  const float* srm1_a = sched + 200;
  const float* c1_a   = sched + 400;
  const float* c2_a   = sched + 600;
  const float* sg_a   = sched + 800;

#pragma unroll 1
  for (int t = 199; t >= 0; --t) {
    // fold_in(key(2), t): wave-uniform -> SALU, overlaps VALU
    uint32_t fk0, fk1;
    threefry2x32(0u, 2u, 0u, (uint32_t)t, fk0, fk1);

    const float tp = tpb[t * 64 + lane];
    // GEMV-in: 4 partial accumulators per row -> 8 independent chains
    float aA0 = tp + cpA, aA1 = 0.f, aA2 = 0.f, aA3 = 0.f;
    float aB0 = tp + cpB, aB1 = 0.f, aB2 = 0.f, aB3 = 0.f;
    {
      int xiA = __float_as_int(xA), xiB = __float_as_int(xB);
#pragma unroll
      for (int k = 0; k < 16; ++k) {
        float a0 = __int_as_float(__builtin_amdgcn_readlane(xiA, 4 * k + 0));
        float a1 = __int_as_float(__builtin_amdgcn_readlane(xiA, 4 * k + 1));
        float a2 = __int_as_float(__builtin_amdgcn_readlane(xiA, 4 * k + 2));
        float a3 = __int_as_float(__builtin_amdgcn_readlane(xiA, 4 * k + 3));
        float b0 = __int_as_float(__builtin_amdgcn_readlane(xiB, 4 * k + 0));
        float b1 = __int_as_float(__builtin_amdgcn_readlane(xiB, 4 * k + 1));
        float b2 = __int_as_float(__builtin_amdgcn_readlane(xiB, 4 * k + 2));
        float b3 = __int_as_float(__builtin_amdgcn_readlane(xiB, 4 * k + 3));
        aA0 = fmaf(a0, Wi[4 * k + 0], aA0);
        aA1 = fmaf(a1, Wi[4 * k + 1], aA1);
        aA2 = fmaf(a2, Wi[4 * k + 2], aA2);
        aA3 = fmaf(a3, Wi[4 * k + 3], aA3);
        aB0 = fmaf(b0, Wi[4 * k + 0], aB0);
        aB1 = fmaf(b1, Wi[4 * k + 1], aB1);
        aB2 = fmaf(b2, Wi[4 * k + 2], aB2);
        aB3 = fmaf(b3, Wi[4 * k + 3], aB3);
      }
    }
    float aA = (aA0 + aA1) + (aA2 + aA3);
    float aB = (aB0 + aB1) + (aB2 + aB3);

    // silu via fast rcp (~1 ulp)
    float hA = aA * __builtin_amdgcn_rcpf(1.0f + __expf(-aA));
    float hB = aB * __builtin_amdgcn_rcpf(1.0f + __expf(-aB));

    // GEMV-out
    float eA0 = bo, eA1 = 0.f, eA2 = 0.f, eA3 = 0.f;
    float eB0 = bo, eB1 = 0.f, eB2 = 0.f, eB3 = 0.f;
    {
      int hiA = __float_as_int(hA), hiB = __float_as_int(hB);
#pragma unroll
      for (int k = 0; k < 16; ++k) {
        float a0 = __int_as_float(__builtin_amdgcn_readlane(hiA, 4 * k + 0));
        float a1 = __int_as_float(__builtin_amdgcn_readlane(hiA, 4 * k + 1));
        float a2 = __int_as_float(__builtin_amdgcn_readlane(hiA, 4 * k + 2));
        float a3 = __int_as_float(__builtin_amdgcn_readlane(hiA, 4 * k + 3));
        float b0 = __int_as_float(__builtin_amdgcn_readlane(hiB, 4 * k + 0));
        float b1 = __int_as_float(__builtin_amdgcn_readlane(hiB, 4 * k + 1));
        float b2 = __int_as_float(__builtin_amdgcn_readlane(hiB, 4 * k + 2));
        float b3 = __int_as_float(__builtin_amdgcn_readlane(hiB, 4 * k + 3));
        eA0 = fmaf(a0, Wo[4 * k + 0], eA0);
        eA1 = fmaf(a1, Wo[4 * k + 1], eA1);
        eA2 = fmaf(a2, Wo[4 * k + 2], eA2);
        eA3 = fmaf(a3, Wo[4 * k + 3], eA3);
        eB0 = fmaf(b0, Wo[4 * k + 0], eB0);
        eB1 = fmaf(b1, Wo[4 * k + 1], eB1);
        eB2 = fmaf(b2, Wo[4 * k + 2], eB2);
        eB3 = fmaf(b3, Wo[4 * k + 3], eB3);
      }
    }
    float eA = (eA0 + eA1) + (eA2 + eA3);
    float eB = (eB0 + eB1) + (eB2 + eB3);

    const float sr = sr_a[t], srm1 = srm1_a[t];
    const float c1 = c1_a[t], c2 = c2_a[t], sg = sg_a[t];

    float x0A = fminf(1.f, fmaxf(-1.f, sr * xA - srm1 * eA));
    float x0B = fminf(1.f, fmaxf(-1.f, sr * xB - srm1 * eB));

    float nA = jax_bits_to_normal(jax_random_bits32(fk0, fk1, jA));
    float nB = jax_bits_to_normal(jax_random_bits32(fk0, fk1, jB));

    xA = c1 * x0A + c2 * xA + sg * nA;
    xB = c1 * x0B + c2 * xB + sg * nB;
  }

  out[p * 64 + lane]            = xA;
  out[(p + 4096) * 64 + lane]   = xB;
}

// ---------------------------------------------------------------------------
extern "C" void kernel_launch(void* const* d_in, const int* in_sizes, int n_in,
                              void* d_out, int out_size, void* d_ws, size_t ws_size,
                              hipStream_t stream)
{
  const int*   seq  = (const int*)  d_in[0];
  const float* emb  = (const float*)d_in[1];
  const float* W1   = (const float*)d_in[2];
  const float* b1   = (const float*)d_in[3];
  const float* W2   = (const float*)d_in[4];
  const float* b2   = (const float*)d_in[5];
  const float* Win  = (const float*)d_in[6];
  const float* bin  = (const float*)d_in[7];
  const float* Wt   = (const float*)d_in[8];
  const float* bt   = (const float*)d_in[9];
  const float* Wc   = (const float*)d_in[10];
  const float* bc   = (const float*)d_in[11];
  const float* Wout = (const float*)d_in[12];
  const float* bout = (const float*)d_in[13];

  float* out   = (float*)d_out;
  float* ws    = (float*)d_ws;
  float* cproj = ws;                       // 524288 floats
  float* tpb   = ws + 524288;              // 12800 floats
  float* sched = ws + 524288 + 12800;      // 1000 floats
  float* pooled = out;                     // reuse d_out as scratch

  k_pool <<<2048, 256, 0, stream>>>(seq, emb, pooled);
  k_enc  <<<1024, 256, 0, stream>>>(pooled, W1, b1, W2, b2, Wc, bc, cproj);
  k_sched<<<1, 64, 0, stream>>>(sched);
  k_tproj<<<200, 64, 0, stream>>>(Wt, bt, bin, tpb);
  k_ddpm <<<1024, 256, 0, stream>>>(Win, Wout, bout, cproj, tpb, sched, out);
}